// Round 22
// baseline (296.160 us; speedup 1.0000x reference)
//
#include <hip/hip_runtime.h>
#include <hip/hip_bf16.h>
#include <math.h>

// Problem constants
#define BB 4
#define SS 4096
#define DD 1024
#define NN 128           // D / 8
#define KLV 8            // quantization levels
#define MM (BB*SS)       // 16384 rows
#define NST 64           // K substeps of 32 over x_cat (2048)

typedef short bf16x8 __attribute__((ext_vector_type(8)));
typedef float f32x4 __attribute__((ext_vector_type(4)));

// Static device scratch.
__device__ unsigned short g_U16[KLV * NN * 128];   // 256 KB Cayley table (bf16)
__device__ unsigned char g_levels[MM * NN];        // 2 MB   per-(token,block) level
__device__ unsigned short g_XH[(size_t)MM * 2048]; // 64 MB  xh = bf16(x_cat), row-major
// W pre-subtiled: elem = (((st*2 + plane)*4 + kgrp)*1024 + n)*8 + kin   (8 MB)
__device__ unsigned short g_WTs[(size_t)NST * 2 * 4 * 1024 * 8];

// f32 -> bf16 bits, round-to-nearest-even
__device__ __forceinline__ unsigned int bf16_bits(float f) {
    union { float f; unsigned int u; } v;
    v.f = f;
    unsigned int lsb = (v.u >> 16) & 1u;
    return (v.u + 0x7FFFu + lsb) >> 16;
}
__device__ __forceinline__ float bfbits2f(unsigned int b) {
    union { unsigned int u; float f; } v;
    v.u = b << 16;
    return v.f;
}

// ---------------------------------------------------------------------------
// prep_kernel: {convert_x | convert_wt | cayley} by blockIdx range.
// ---------------------------------------------------------------------------
#define WT_BLOCKS (64 * 32)
__global__ __launch_bounds__(256)
void prep_kernel(const float* __restrict__ xr, const float* __restrict__ xi,
                 const float* __restrict__ W,
                 const float* __restrict__ A_real,
                 const float* __restrict__ A_imag)
{
    __shared__ __align__(16) float sh[33 * 32];
    int blk = blockIdx.x;
    int t = threadIdx.x;

    if (blk < MM) {
        // ---- convert_x: row m of x_cat -> g_XH bf16 (hi only) ----
        int m = blk;
        const float* src = (t < 128) ? xr : xi;
        int off = (t & 127) * 8;
        const float* p = src + (size_t)m * DD + off;
        float4 v0 = *(const float4*)p;
        float4 v1 = *(const float4*)(p + 4);
        float f[8] = {v0.x, v0.y, v0.z, v0.w, v1.x, v1.y, v1.z, v1.w};
        unsigned int h[8];
        #pragma unroll
        for (int q = 0; q < 8; ++q) h[q] = bf16_bits(f[q]);
        *(uint4*)&g_XH[(size_t)m * 2048 + t * 8] = make_uint4(
            h[0] | (h[1] << 16), h[2] | (h[3] << 16),
            h[4] | (h[5] << 16), h[6] | (h[7] << 16));
        return;
    }
    blk -= MM;

    if (blk < WT_BLOCKS) {
        // ---- convert_wt: W[k][n] -> g_WTs subtiled hi|lo (32x32 transpose) ----
        float (*tile)[33] = (float(*)[33])sh;
        int bk = (blk >> 5) * 32;
        int bn = (blk & 31) * 32;

        int kk = t >> 3;
        int nn4 = (t & 7) * 4;
        float4 v = *(const float4*)&W[(size_t)(bk + kk) * DD + bn + nn4];
        tile[kk][nn4 + 0] = v.x; tile[kk][nn4 + 1] = v.y;
        tile[kk][nn4 + 2] = v.z; tile[kk][nn4 + 3] = v.w;
        __syncthreads();

        int n2 = t >> 3;                   // 0..31 (output n within tile)
        int k4i = (t & 7) * 4;             // 0..28, 4 consecutive k
        unsigned int hi[4], lo[4];
        #pragma unroll
        for (int q = 0; q < 4; ++q) {
            float f = tile[k4i + q][n2];
            hi[q] = bf16_bits(f);
            lo[q] = bf16_bits(f - bfbits2f(hi[q]));
        }
        int st = bk >> 5;
        int kgrp = (k4i >> 3) & 3;
        int kin = k4i & 7;                 // 0 or 4
        int n = bn + n2;
        size_t bh = ((size_t)((st * 2 + 0) * 4 + kgrp) * 1024 + n) * 8 + kin;
        size_t bl = ((size_t)((st * 2 + 1) * 4 + kgrp) * 1024 + n) * 8 + kin;
        *(uint2*)&g_WTs[bh] = make_uint2(hi[0] | (hi[1] << 16), hi[2] | (hi[3] << 16));
        *(uint2*)&g_WTs[bl] = make_uint2(lo[0] | (lo[1] << 16), lo[2] | (lo[3] << 16));
        return;
    }
    blk -= WT_BLOCKS;

    {
        // ---- cayley: Gauss-Jordan on 16x16 augmented system; store bf16 ----
        float (*M)[34] = (float(*)[34])sh;
        int L = blk >> 7;
        int n = blk & 127;
        float g = (float)L * (1.0f / 7.0f);

        int i = t >> 4;
        int j = t & 15;

        const float* Ar = A_real + n * 64;
        const float* Ai = A_imag + n * 64;
        int bi = i >> 3;
        int ii = i & 7, jj = j & 7;

        float ar = (Ar[ii * 8 + jj] - Ar[jj * 8 + ii]) * 0.5f * g;
        float ai = (Ai[ii * 8 + jj] + Ai[jj * 8 + ii]) * 0.5f * g;
        float eye = (ii == jj) ? 1.0f : 0.0f;

        int bj = j >> 3;
        float lhs, rhs;
        if (bi == bj) { lhs = eye + ar; rhs = eye - ar; }
        else if (bi == 0) { lhs = -ai; rhs = ai; }
        else { lhs = ai; rhs = -ai; }

        M[i][j] = lhs;
        M[i][16 + j] = rhs;
        __syncthreads();

        for (int k = 0; k < 16; ++k) {
            float f = M[i][k] / M[k][k];
            __syncthreads();
            if (i != k) {
                M[i][j]      -= f * M[k][j];
                M[i][16 + j] -= f * M[k][16 + j];
            }
            __syncthreads();
        }

        float x = M[i][16 + j] / M[i][i];
        if (j < 8) {
            g_U16[(size_t)blk * 128 + bi * 64 + ii * 8 + j] =
                (unsigned short)bf16_bits(x);
        }
    }
}

// ---------------------------------------------------------------------------
// gate_v8: BARRIER-FREE, LDS-FREE fragment GEMM. 128x256 block tile, 4
// independent waves (each owns 128x64 output). Per substep each wave loads
// its A-frags straight from g_XH (bf16, pre-converted) and B-frags from
// g_WTs — both L2-resident — then 64 MFMA. No LDS, no barriers, no waitcnt:
// waves free-run, TLP + compiler pipelining hide L2 latency.
//   z = xh*wh + xh*wl  (two-term split; values & order == round 18)
// ---------------------------------------------------------------------------
__global__ __launch_bounds__(256, 2)
void gate_v8(const float* __restrict__ bias)
{
    const int tid = threadIdx.x;
    const int bid = blockIdx.x;          // 0..511
    const int xcd = bid & 7;             // dispatch round-robins XCDs [m09]
    const int grp = bid >> 3;            // 0..63
    const int mt = xcd * 16 + (grp >> 2);// 0..127 : 4 n-tiles of an m-strip
    const int nt = grp & 3;              //          co-resident on one XCD
    const int bm = mt * 128, bn = nt * 256;

    const int lane = tid & 63;
    const int wc = tid >> 6;             // 4 waves = 4 N-columns
    const int r16 = lane & 15, sgrp = lane >> 4;

    f32x4 acc[8][4];
    #pragma unroll
    for (int a = 0; a < 8; ++a)
        #pragma unroll
        for (int b = 0; b < 4; ++b) {
            f32x4 z = {0.0f, 0.0f, 0.0f, 0.0f};
            acc[a][b] = z;
        }

    // Per-lane constant bases (affine in st).
    const unsigned short* Abase = g_XH + (size_t)(bm + r16) * 2048 + sgrp * 8;
    const unsigned short* Bbase = g_WTs + ((size_t)sgrp * 1024 +
                                           (bn + wc * 64 + r16)) * 8;

    for (int st = 0; st < NST; ++st) {
        // B frags: wh & wl planes of substep st (L2-resident, 2MB/XCD slice).
        bf16x8 whf[4], wlf[4], ahf[8];
        #pragma unroll
        for (int ni = 0; ni < 4; ++ni) {
            whf[ni] = *(const bf16x8*)(Bbase +
                ((size_t)(st * 2 + 0) * 4 * 1024 + ni * 16) * 8);
            wlf[ni] = *(const bf16x8*)(Bbase +
                ((size_t)(st * 2 + 1) * 4 * 1024 + ni * 16) * 8);
        }
        // A frags: 8 x 16-row fragments of the block's 128-row strip.
        #pragma unroll
        for (int mi = 0; mi < 8; ++mi)
            ahf[mi] = *(const bf16x8*)(Abase + (size_t)mi * 16 * 2048 + st * 32);

        // term 1: hi * wh
        __builtin_amdgcn_s_setprio(1);
        #pragma unroll
        for (int mi = 0; mi < 8; ++mi)
            #pragma unroll
            for (int ni = 0; ni < 4; ++ni)
                acc[mi][ni] = __builtin_amdgcn_mfma_f32_16x16x32_bf16(
                    ahf[mi], whf[ni], acc[mi][ni], 0, 0, 0);
        __builtin_amdgcn_s_setprio(0);
        // term 2: hi * wl
        __builtin_amdgcn_s_setprio(1);
        #pragma unroll
        for (int mi = 0; mi < 8; ++mi)
            #pragma unroll
            for (int ni = 0; ni < 4; ++ni)
                acc[mi][ni] = __builtin_amdgcn_mfma_f32_16x16x32_bf16(
                    ahf[mi], wlf[ni], acc[mi][ni], 0, 0, 0);
        __builtin_amdgcn_s_setprio(0);
    }

    // Epilogue: z = (c + bias)*1.7015 -> sigmoid -> mean over 8 cols -> level
    #pragma unroll
    for (int mi = 0; mi < 8; ++mi) {
        #pragma unroll
        for (int ni = 0; ni < 4; ++ni) {
            int n = bn + wc * 64 + ni * 16 + r16;
            float bb = bias[n];
            #pragma unroll
            for (int r = 0; r < 4; ++r) {
                float z = (acc[mi][ni][r] + bb) * 1.7015f;
                float s = 1.0f / (1.0f + expf(-z));
                s += __shfl_xor(s, 1);
                s += __shfl_xor(s, 2);
                s += __shfl_xor(s, 4);
                if ((lane & 7) == 0) {
                    float gcont = s * 0.125f;
                    int lvl = (int)rintf(gcont * 7.0f);
                    lvl = min(7, max(0, lvl));
                    int m = bm + mi * 16 + sgrp * 4 + r;
                    g_levels[(size_t)m * NN + (n >> 3)] = (unsigned char)lvl;
                }
            }
        }
    }
}

// ---------------------------------------------------------------------------
// apply: gather bf16 U by level, rotate in f32, blend, write bf16 [imag, real].
// ---------------------------------------------------------------------------
__global__ __launch_bounds__(256)
void apply_kernel(const float* __restrict__ xr,
                  const float* __restrict__ xi,
                  unsigned short* __restrict__ out)
{
    int t = blockIdx.x * 256 + threadIdx.x;
    int bs = t >> 7;
    int n = t & 127;

    int L = g_levels[t];
    const unsigned short* Up = g_U16 + (size_t)(L * NN + n) * 128;
    const float* xrp = xr + (size_t)bs * DD + n * 8;
    const float* xip = xi + (size_t)bs * DD + n * 8;

    float4 r0 = *(const float4*)xrp;
    float4 r1 = *(const float4*)(xrp + 4);
    float4 i0 = *(const float4*)xip;
    float4 i1 = *(const float4*)(xip + 4);
    float xrv[8] = {r0.x, r0.y, r0.z, r0.w, r1.x, r1.y, r1.z, r1.w};
    float xiv[8] = {i0.x, i0.y, i0.z, i0.w, i1.x, i1.y, i1.z, i1.w};

    float gq = (float)L * (1.0f / 7.0f);
    float scale = gq / (gq + 1e-7f);

    unsigned int pk[8];
    #pragma unroll
    for (int oo = 0; oo < 8; ++oo) {
        uint4 uw = *(const uint4*)&Up[oo * 8];        // 8 bf16 of U_r row
        uint4 vw = *(const uint4*)&Up[64 + oo * 8];   // 8 bf16 of U_i row
        unsigned int uwa[4] = {uw.x, uw.y, uw.z, uw.w};
        unsigned int vwa[4] = {vw.x, vw.y, vw.z, vw.w};
        float ur[8], ui[8];
        #pragma unroll
        for (int q = 0; q < 4; ++q) {
            ur[2*q]   = bfbits2f(uwa[q] & 0xFFFFu);
            ur[2*q+1] = bfbits2f(uwa[q] >> 16);
            ui[2*q]   = bfbits2f(vwa[q] & 0xFFFFu);
            ui[2*q+1] = bfbits2f(vwa[q] >> 16);
        }
        float uxr = 0.0f, uxi = 0.0f;
        #pragma unroll
        for (int q = 0; q < 8; ++q) {
            uxr += ur[q] * xrv[q] - ui[q] * xiv[q];
            uxi += ur[q] * xiv[q] + ui[q] * xrv[q];
        }
        float outr = xrv[oo] + scale * (uxr - xrv[oo]);
        float outi = xiv[oo] + scale * (uxi - xiv[oo]);
        pk[oo] = bf16_bits(outi) | (bf16_bits(outr) << 16);   // [imag, real]
    }

    unsigned int* ob = (unsigned int*)(out + 2 * ((size_t)bs * DD + (size_t)n * 8));
    *(uint4*)&ob[0] = make_uint4(pk[0], pk[1], pk[2], pk[3]);
    *(uint4*)&ob[4] = make_uint4(pk[4], pk[5], pk[6], pk[7]);
}

// ---------------------------------------------------------------------------
extern "C" void kernel_launch(void* const* d_in, const int* in_sizes, int n_in,
                              void* d_out, int out_size, void* d_ws, size_t ws_size,
                              hipStream_t stream) {
    (void)in_sizes; (void)n_in; (void)out_size; (void)d_ws; (void)ws_size;
    const float* x_real = (const float*)d_in[0];
    const float* x_imag = (const float*)d_in[1];
    const float* A_real = (const float*)d_in[2];
    const float* A_imag = (const float*)d_in[3];
    const float* W_gate = (const float*)d_in[4];
    const float* b_gate = (const float*)d_in[5];
    unsigned short* out = (unsigned short*)d_out;

    hipLaunchKernelGGL(prep_kernel, dim3(MM + WT_BLOCKS + KLV * NN), dim3(256),
                       0, stream, x_real, x_imag, W_gate, A_real, A_imag);
    hipLaunchKernelGGL(gate_v8, dim3(512), dim3(256), 0, stream, b_gate);
    hipLaunchKernelGGL(apply_kernel, dim3((MM * NN) / 256), dim3(256), 0, stream,
                       x_real, x_imag, out);
}

// Round 23
// 229.990 us; speedup vs baseline: 1.2877x; 1.2877x over previous
//
#include <hip/hip_runtime.h>
#include <hip/hip_bf16.h>
#include <math.h>

// Problem constants
#define BB 4
#define SS 4096
#define DD 1024
#define NN 128           // D / 8
#define KLV 8            // quantization levels
#define MM (BB*SS)       // 16384 rows
#define NST 64           // K substeps of 32 over x_cat (2048)

typedef short bf16x8 __attribute__((ext_vector_type(8)));
typedef float f32x4 __attribute__((ext_vector_type(4)));

// Static device scratch.
__device__ unsigned short g_U16[KLV * NN * 128];   // 256 KB Cayley table (bf16)
__device__ unsigned char g_levels[MM * NN];        // 2 MB   per-(token,block) level
// W pre-subtiled: elem = (((st*2 + plane)*4 + kgrp)*1024 + n)*8 + kin   (8 MB)
__device__ unsigned short g_WTs[(size_t)NST * 2 * 4 * 1024 * 8];

// f32 -> bf16 bits, round-to-nearest-even
__device__ __forceinline__ unsigned int bf16_bits(float f) {
    union { float f; unsigned int u; } v;
    v.f = f;
    unsigned int lsb = (v.u >> 16) & 1u;
    return (v.u + 0x7FFFu + lsb) >> 16;
}
__device__ __forceinline__ float bfbits2f(unsigned int b) {
    union { unsigned int u; float f; } v;
    v.u = b << 16;
    return v.f;
}

// ---------------------------------------------------------------------------
// prep_kernel: {convert_wt | cayley} by blockIdx range.
// ---------------------------------------------------------------------------
#define WT_BLOCKS (64 * 32)
__global__ __launch_bounds__(256)
void prep_kernel(const float* __restrict__ W,
                 const float* __restrict__ A_real,
                 const float* __restrict__ A_imag)
{
    __shared__ __align__(16) float sh[33 * 32];
    int blk = blockIdx.x;
    int t = threadIdx.x;

    if (blk < WT_BLOCKS) {
        // ---- convert_wt: W[k][n] -> g_WTs subtiled hi|lo (32x32 transpose) ----
        float (*tile)[33] = (float(*)[33])sh;
        int bk = (blk >> 5) * 32;
        int bn = (blk & 31) * 32;

        int kk = t >> 3;
        int nn4 = (t & 7) * 4;
        float4 v = *(const float4*)&W[(size_t)(bk + kk) * DD + bn + nn4];
        tile[kk][nn4 + 0] = v.x; tile[kk][nn4 + 1] = v.y;
        tile[kk][nn4 + 2] = v.z; tile[kk][nn4 + 3] = v.w;
        __syncthreads();

        int n2 = t >> 3;                   // 0..31 (output n within tile)
        int k4i = (t & 7) * 4;             // 0..28, 4 consecutive k
        unsigned int hi[4], lo[4];
        #pragma unroll
        for (int q = 0; q < 4; ++q) {
            float f = tile[k4i + q][n2];
            hi[q] = bf16_bits(f);
            lo[q] = bf16_bits(f - bfbits2f(hi[q]));
        }
        int st = bk >> 5;
        int kgrp = (k4i >> 3) & 3;
        int kin = k4i & 7;                 // 0 or 4
        int n = bn + n2;
        size_t bh = ((size_t)((st * 2 + 0) * 4 + kgrp) * 1024 + n) * 8 + kin;
        size_t bl = ((size_t)((st * 2 + 1) * 4 + kgrp) * 1024 + n) * 8 + kin;
        *(uint2*)&g_WTs[bh] = make_uint2(hi[0] | (hi[1] << 16), hi[2] | (hi[3] << 16));
        *(uint2*)&g_WTs[bl] = make_uint2(lo[0] | (lo[1] << 16), lo[2] | (lo[3] << 16));
        return;
    }
    blk -= WT_BLOCKS;

    {
        // ---- cayley: Gauss-Jordan on 16x16 augmented system; store bf16 ----
        float (*M)[34] = (float(*)[34])sh;
        int L = blk >> 7;
        int n = blk & 127;
        float g = (float)L * (1.0f / 7.0f);

        int i = t >> 4;
        int j = t & 15;

        const float* Ar = A_real + n * 64;
        const float* Ai = A_imag + n * 64;
        int bi = i >> 3;
        int ii = i & 7, jj = j & 7;

        float ar = (Ar[ii * 8 + jj] - Ar[jj * 8 + ii]) * 0.5f * g;
        float ai = (Ai[ii * 8 + jj] + Ai[jj * 8 + ii]) * 0.5f * g;
        float eye = (ii == jj) ? 1.0f : 0.0f;

        int bj = j >> 3;
        float lhs, rhs;
        if (bi == bj) { lhs = eye + ar; rhs = eye - ar; }
        else if (bi == 0) { lhs = -ai; rhs = ai; }
        else { lhs = ai; rhs = -ai; }

        M[i][j] = lhs;
        M[i][16 + j] = rhs;
        __syncthreads();

        for (int k = 0; k < 16; ++k) {
            float f = M[i][k] / M[k][k];
            __syncthreads();
            if (i != k) {
                M[i][j]      -= f * M[k][j];
                M[i][16 + j] -= f * M[k][16 + j];
            }
            __syncthreads();
        }

        float x = M[i][16 + j] / M[i][i];
        if (j < 8) {
            g_U16[(size_t)blk * 128 + bi * 64 + ii * 8 + j] =
                (unsigned short)bf16_bits(x);
        }
    }
}

// ---------------------------------------------------------------------------
// gate_v4: 128x256 tile, 4 waves, 2 blocks/CU. TWO-term split GEMM:
//   z = xh*wh + xh*wl   (x rounded to bf16; W keeps its lo correction).
//  - A: f32 from HBM -> in-register bf16 (hi only) -> LDS (8KB/buf, dbuf 16KB).
//  - B: direct per-lane global_load from L2-resident g_WTs (wh + wl planes).
//  - A-hi frags register-cached across both terms.
// LDS map per buf (shorts): A_hi[4][128][8]; bufs @0,@4096.
// Best-known configuration (round 18: 230.3 us total, absmax 0.0859375).
// ---------------------------------------------------------------------------
__global__ __launch_bounds__(256, 2)
void gate_v4(const float* __restrict__ xr, const float* __restrict__ xi,
             const float* __restrict__ bias)
{
    __shared__ __align__(16) unsigned short lds[8192];   // 16 KB

    const int tid = threadIdx.x;
    const int bid = blockIdx.x;          // 0..511
    const int xcd = bid & 7;             // dispatch round-robins XCDs [m09]
    const int grp = bid >> 3;            // 0..63
    const int mt = xcd * 16 + (grp >> 2);// 0..127 : 4 n-tiles of an m-strip
    const int nt = grp & 3;              //          co-resident on one XCD
    const int bm = mt * 128, bn = nt * 256;

    const int lane = tid & 63;
    const int wc = tid >> 6;             // 4 waves = 4 N-columns
    const int r16 = lane & 15, sgrp = lane >> 4;

    const int arow = tid >> 1;           // staging row 0..127
    const int kb = (tid & 1) * 2;        // staging kgrp base (0 or 2)

    f32x4 acc[8][4];
    #pragma unroll
    for (int a = 0; a < 8; ++a)
        #pragma unroll
        for (int b = 0; b < 4; ++b) {
            f32x4 z = {0.0f, 0.0f, 0.0f, 0.0f};
            acc[a][b] = z;
        }

    // Load 16 f32 of substep s (clamped) into 4 float4 regs.
    #define LOADX(dst, s)                                                         \
    {                                                                             \
        int s_ = (s) > 63 ? 63 : (s);                                             \
        int k0_ = s_ * 32;                                                        \
        const float* src_ = (k0_ < 1024) ? xr : xi;                               \
        const float* p_ = src_ + (size_t)(bm + arow) * DD + (k0_ & 1023)          \
                          + (tid & 1) * 16;                                       \
        (dst)[0] = *(const float4*)(p_);                                          \
        (dst)[1] = *(const float4*)(p_ + 4);                                      \
        (dst)[2] = *(const float4*)(p_ + 8);                                      \
        (dst)[3] = *(const float4*)(p_ + 12);                                     \
    }

    // Convert 16 f32 -> hi bf16 only, write 2x b128 into buffer base bb.
    #define WRITEA(fv, bb)                                                        \
    {                                                                             \
        float ff_[16] = {(fv)[0].x, (fv)[0].y, (fv)[0].z, (fv)[0].w,              \
                         (fv)[1].x, (fv)[1].y, (fv)[1].z, (fv)[1].w,              \
                         (fv)[2].x, (fv)[2].y, (fv)[2].z, (fv)[2].w,              \
                         (fv)[3].x, (fv)[3].y, (fv)[3].z, (fv)[3].w};             \
        unsigned int h_[16];                                                      \
        _Pragma("unroll")                                                         \
        for (int q = 0; q < 16; ++q) h_[q] = bf16_bits(ff_[q]);                   \
        _Pragma("unroll")                                                         \
        for (int b2 = 0; b2 < 2; ++b2) {                                          \
            int o_ = ((kb + b2) * 128 + arow) * 8;                                \
            *(uint4*)&lds[(bb) + o_] = make_uint4(                                \
                h_[b2*8+0] | (h_[b2*8+1] << 16), h_[b2*8+2] | (h_[b2*8+3] << 16), \
                h_[b2*8+4] | (h_[b2*8+5] << 16), h_[b2*8+6] | (h_[b2*8+7] << 16));\
        }                                                                         \
    }

    // A frag from LDS; B frag direct from L2-resident g_WTs.
    #define RA(bb, mi) (*(const bf16x8*)&lds[(bb) + \
        (sgrp * 128 + (mi) * 16 + r16) * 8])
    #define BW(s, plane, ni) (*(const bf16x8*)&g_WTs[ \
        ((size_t)((((s) > 63 ? 63 : (s)) * 2 + (plane)) * 4 + sgrp) * 1024 + \
         (bn + wc * 64 + (ni) * 16 + r16)) * 8])

    // ---- Prologue: stage substep 0; preload f32(1). ----
    float4 fst[4], ftmp[4];
    LOADX(fst, 0);
    WRITEA(fst, 0);
    LOADX(fst, 1);
    asm volatile("s_waitcnt lgkmcnt(0)" ::: "memory");
    __builtin_amdgcn_s_barrier();

    for (int st = 0; st < NST; ++st) {
        const int bcur = (st & 1) * 4096;
        const int bnxt = bcur ^ 4096;

        // Issue B(st) loads first: WRITEA's conversion VALU covers L2 latency.
        bf16x8 whf[4], wlf[4], ahi[8];
        #pragma unroll
        for (int ni = 0; ni < 4; ++ni) whf[ni] = BW(st, 0, ni);
        #pragma unroll
        for (int ni = 0; ni < 4; ++ni) wlf[ni] = BW(st, 1, ni);

        // Stage st+1 into nxt; issue f32(st+2).
        WRITEA(fst, bnxt);
        LOADX(ftmp, st + 2);

        #pragma unroll
        for (int mi = 0; mi < 8; ++mi) ahi[mi] = RA(bcur, mi);

        // term 1: hi * wh
        __builtin_amdgcn_s_setprio(1);
        #pragma unroll
        for (int mi = 0; mi < 8; ++mi)
            #pragma unroll
            for (int ni = 0; ni < 4; ++ni)
                acc[mi][ni] = __builtin_amdgcn_mfma_f32_16x16x32_bf16(
                    ahi[mi], whf[ni], acc[mi][ni], 0, 0, 0);
        __builtin_amdgcn_s_setprio(0);
        // term 2: hi * wl  (A-hi register-cached)
        __builtin_amdgcn_s_setprio(1);
        #pragma unroll
        for (int mi = 0; mi < 8; ++mi)
            #pragma unroll
            for (int ni = 0; ni < 4; ++ni)
                acc[mi][ni] = __builtin_amdgcn_mfma_f32_16x16x32_bf16(
                    ahi[mi], wlf[ni], acc[mi][ni], 0, 0, 0);
        __builtin_amdgcn_s_setprio(0);

        // A-dbuf sync (4 waves; co-resident block covers the stall).
        asm volatile("s_waitcnt lgkmcnt(0)" ::: "memory");
        __builtin_amdgcn_s_barrier();
        #pragma unroll
        for (int q = 0; q < 4; ++q) fst[q] = ftmp[q];
    }
    #undef LOADX
    #undef WRITEA
    #undef RA
    #undef BW

    // Epilogue: z = (c + bias)*1.7015 -> sigmoid -> mean over 8 cols -> level
    #pragma unroll
    for (int mi = 0; mi < 8; ++mi) {
        #pragma unroll
        for (int ni = 0; ni < 4; ++ni) {
            int n = bn + wc * 64 + ni * 16 + r16;
            float bb = bias[n];
            #pragma unroll
            for (int r = 0; r < 4; ++r) {
                float z = (acc[mi][ni][r] + bb) * 1.7015f;
                float s = 1.0f / (1.0f + expf(-z));
                s += __shfl_xor(s, 1);
                s += __shfl_xor(s, 2);
                s += __shfl_xor(s, 4);
                if ((lane & 7) == 0) {
                    float gcont = s * 0.125f;
                    int lvl = (int)rintf(gcont * 7.0f);
                    lvl = min(7, max(0, lvl));
                    int m = bm + mi * 16 + sgrp * 4 + r;
                    g_levels[(size_t)m * NN + (n >> 3)] = (unsigned char)lvl;
                }
            }
        }
    }
}

// ---------------------------------------------------------------------------
// apply: gather bf16 U by level, rotate in f32, blend, write bf16 [imag, real].
// ---------------------------------------------------------------------------
__global__ __launch_bounds__(256)
void apply_kernel(const float* __restrict__ xr,
                  const float* __restrict__ xi,
                  unsigned short* __restrict__ out)
{
    int t = blockIdx.x * 256 + threadIdx.x;
    int bs = t >> 7;
    int n = t & 127;

    int L = g_levels[t];
    const unsigned short* Up = g_U16 + (size_t)(L * NN + n) * 128;
    const float* xrp = xr + (size_t)bs * DD + n * 8;
    const float* xip = xi + (size_t)bs * DD + n * 8;

    float4 r0 = *(const float4*)xrp;
    float4 r1 = *(const float4*)(xrp + 4);
    float4 i0 = *(const float4*)xip;
    float4 i1 = *(const float4*)(xip + 4);
    float xrv[8] = {r0.x, r0.y, r0.z, r0.w, r1.x, r1.y, r1.z, r1.w};
    float xiv[8] = {i0.x, i0.y, i0.z, i0.w, i1.x, i1.y, i1.z, i1.w};

    float gq = (float)L * (1.0f / 7.0f);
    float scale = gq / (gq + 1e-7f);

    unsigned int pk[8];
    #pragma unroll
    for (int oo = 0; oo < 8; ++oo) {
        uint4 uw = *(const uint4*)&Up[oo * 8];        // 8 bf16 of U_r row
        uint4 vw = *(const uint4*)&Up[64 + oo * 8];   // 8 bf16 of U_i row
        unsigned int uwa[4] = {uw.x, uw.y, uw.z, uw.w};
        unsigned int vwa[4] = {vw.x, vw.y, vw.z, vw.w};
        float ur[8], ui[8];
        #pragma unroll
        for (int q = 0; q < 4; ++q) {
            ur[2*q]   = bfbits2f(uwa[q] & 0xFFFFu);
            ur[2*q+1] = bfbits2f(uwa[q] >> 16);
            ui[2*q]   = bfbits2f(vwa[q] & 0xFFFFu);
            ui[2*q+1] = bfbits2f(vwa[q] >> 16);
        }
        float uxr = 0.0f, uxi = 0.0f;
        #pragma unroll
        for (int q = 0; q < 8; ++q) {
            uxr += ur[q] * xrv[q] - ui[q] * xiv[q];
            uxi += ur[q] * xiv[q] + ui[q] * xrv[q];
        }
        float outr = xrv[oo] + scale * (uxr - xrv[oo]);
        float outi = xiv[oo] + scale * (uxi - xiv[oo]);
        pk[oo] = bf16_bits(outi) | (bf16_bits(outr) << 16);   // [imag, real]
    }

    unsigned int* ob = (unsigned int*)(out + 2 * ((size_t)bs * DD + (size_t)n * 8));
    *(uint4*)&ob[0] = make_uint4(pk[0], pk[1], pk[2], pk[3]);
    *(uint4*)&ob[4] = make_uint4(pk[4], pk[5], pk[6], pk[7]);
}

// ---------------------------------------------------------------------------
extern "C" void kernel_launch(void* const* d_in, const int* in_sizes, int n_in,
                              void* d_out, int out_size, void* d_ws, size_t ws_size,
                              hipStream_t stream) {
    (void)in_sizes; (void)n_in; (void)out_size; (void)d_ws; (void)ws_size;
    const float* x_real = (const float*)d_in[0];
    const float* x_imag = (const float*)d_in[1];
    const float* A_real = (const float*)d_in[2];
    const float* A_imag = (const float*)d_in[3];
    const float* W_gate = (const float*)d_in[4];
    const float* b_gate = (const float*)d_in[5];
    unsigned short* out = (unsigned short*)d_out;

    hipLaunchKernelGGL(prep_kernel, dim3(WT_BLOCKS + KLV * NN), dim3(256),
                       0, stream, W_gate, A_real, A_imag);
    hipLaunchKernelGGL(gate_v4, dim3(512), dim3(256), 0, stream,
                       x_real, x_imag, b_gate);
    hipLaunchKernelGGL(apply_kernel, dim3((MM * NN) / 256), dim3(256), 0, stream,
                       x_real, x_imag, out);
}

// Round 24
// 219.838 us; speedup vs baseline: 1.3472x; 1.0462x over previous
//
#include <hip/hip_runtime.h>
#include <hip/hip_bf16.h>
#include <math.h>

// Problem constants
#define BB 4
#define SS 4096
#define DD 1024
#define NN 128           // D / 8
#define KLV 8            // quantization levels
#define MM (BB*SS)       // 16384 rows
#define NST 64           // K substeps of 32 over x_cat (2048)

typedef short bf16x8 __attribute__((ext_vector_type(8)));
typedef float f32x4 __attribute__((ext_vector_type(4)));

// Static device scratch.
__device__ unsigned short g_U16[KLV * NN * 128];   // 256 KB Cayley table (bf16)
// W pre-subtiled: elem = (((st*2 + plane)*4 + kgrp)*1024 + n)*8 + kin   (8 MB)
__device__ unsigned short g_WTs[(size_t)NST * 2 * 4 * 1024 * 8];

// f32 -> bf16 bits, round-to-nearest-even (prep-side; matches v_cvt_pk RNE)
__device__ __forceinline__ unsigned int bf16_bits(float f) {
    union { float f; unsigned int u; } v;
    v.f = f;
    unsigned int lsb = (v.u >> 16) & 1u;
    return (v.u + 0x7FFFu + lsb) >> 16;
}
__device__ __forceinline__ float bfbits2f(unsigned int b) {
    union { unsigned int u; float f; } v;
    v.u = b << 16;
    return v.f;
}

// ---------------------------------------------------------------------------
// prep_kernel: {convert_wt | cayley} by blockIdx range.
// ---------------------------------------------------------------------------
#define WT_BLOCKS (64 * 32)
__global__ __launch_bounds__(256)
void prep_kernel(const float* __restrict__ W,
                 const float* __restrict__ A_real,
                 const float* __restrict__ A_imag)
{
    __shared__ __align__(16) float sh[33 * 32];
    int blk = blockIdx.x;
    int t = threadIdx.x;

    if (blk < WT_BLOCKS) {
        // ---- convert_wt: W[k][n] -> g_WTs subtiled hi|lo (32x32 transpose) ----
        float (*tile)[33] = (float(*)[33])sh;
        int bk = (blk >> 5) * 32;
        int bn = (blk & 31) * 32;

        int kk = t >> 3;
        int nn4 = (t & 7) * 4;
        float4 v = *(const float4*)&W[(size_t)(bk + kk) * DD + bn + nn4];
        tile[kk][nn4 + 0] = v.x; tile[kk][nn4 + 1] = v.y;
        tile[kk][nn4 + 2] = v.z; tile[kk][nn4 + 3] = v.w;
        __syncthreads();

        int n2 = t >> 3;                   // 0..31 (output n within tile)
        int k4i = (t & 7) * 4;             // 0..28, 4 consecutive k
        unsigned int hi[4], lo[4];
        #pragma unroll
        for (int q = 0; q < 4; ++q) {
            float f = tile[k4i + q][n2];
            hi[q] = bf16_bits(f);
            lo[q] = bf16_bits(f - bfbits2f(hi[q]));
        }
        int st = bk >> 5;
        int kgrp = (k4i >> 3) & 3;
        int kin = k4i & 7;                 // 0 or 4
        int n = bn + n2;
        size_t bh = ((size_t)((st * 2 + 0) * 4 + kgrp) * 1024 + n) * 8 + kin;
        size_t bl = ((size_t)((st * 2 + 1) * 4 + kgrp) * 1024 + n) * 8 + kin;
        *(uint2*)&g_WTs[bh] = make_uint2(hi[0] | (hi[1] << 16), hi[2] | (hi[3] << 16));
        *(uint2*)&g_WTs[bl] = make_uint2(lo[0] | (lo[1] << 16), lo[2] | (lo[3] << 16));
        return;
    }
    blk -= WT_BLOCKS;

    {
        // ---- cayley: Gauss-Jordan on 16x16 augmented system; store bf16 ----
        float (*M)[34] = (float(*)[34])sh;
        int L = blk >> 7;
        int n = blk & 127;
        float g = (float)L * (1.0f / 7.0f);

        int i = t >> 4;
        int j = t & 15;

        const float* Ar = A_real + n * 64;
        const float* Ai = A_imag + n * 64;
        int bi = i >> 3;
        int ii = i & 7, jj = j & 7;

        float ar = (Ar[ii * 8 + jj] - Ar[jj * 8 + ii]) * 0.5f * g;
        float ai = (Ai[ii * 8 + jj] + Ai[jj * 8 + ii]) * 0.5f * g;
        float eye = (ii == jj) ? 1.0f : 0.0f;

        int bj = j >> 3;
        float lhs, rhs;
        if (bi == bj) { lhs = eye + ar; rhs = eye - ar; }
        else if (bi == 0) { lhs = -ai; rhs = ai; }
        else { lhs = ai; rhs = -ai; }

        M[i][j] = lhs;
        M[i][16 + j] = rhs;
        __syncthreads();

        for (int k = 0; k < 16; ++k) {
            float f = M[i][k] / M[k][k];
            __syncthreads();
            if (i != k) {
                M[i][j]      -= f * M[k][j];
                M[i][16 + j] -= f * M[k][16 + j];
            }
            __syncthreads();
        }

        float x = M[i][16 + j] / M[i][i];
        if (j < 8) {
            g_U16[(size_t)blk * 128 + bi * 64 + ii * 8 + j] =
                (unsigned short)bf16_bits(x);
        }
    }
}

// ---------------------------------------------------------------------------
// gate_fused: round-18 gate (128x256 tile, 4 waves, 2 blocks/CU, two-term
// split z = xh*wh + xh*wl) with two changes:
//  (1) f32->bf16 conversion via v_cvt_pk_bf16_f32 (1 op / 2 values, RNE —
//      bit-identical to the manual RNE it replaces).
//  (2) apply FUSED into the epilogue: levels kept in LDS only (no global
//      round-trip, no separate kernel); each thread rotates 16 (m,nb) pairs
//      with math identical to the old apply_kernel and writes bf16 [im,re].
// LDS map per buf (shorts): A_hi[4][128][8]; bufs @0,@4096. Levels reuse
// bytes 0..4095 after the final K-loop barrier.
// ---------------------------------------------------------------------------
__global__ __launch_bounds__(256, 2)
void gate_fused(const float* __restrict__ xr, const float* __restrict__ xi,
                const float* __restrict__ bias,
                unsigned short* __restrict__ out)
{
    __shared__ __align__(16) unsigned short lds[8192];   // 16 KB

    const int tid = threadIdx.x;
    const int bid = blockIdx.x;          // 0..511
    const int xcd = bid & 7;             // dispatch round-robins XCDs [m09]
    const int grp = bid >> 3;            // 0..63
    const int mt = xcd * 16 + (grp >> 2);// 0..127 : 4 n-tiles of an m-strip
    const int nt = grp & 3;              //          co-resident on one XCD
    const int bm = mt * 128, bn = nt * 256;

    const int lane = tid & 63;
    const int wc = tid >> 6;             // 4 waves = 4 N-columns
    const int r16 = lane & 15, sgrp = lane >> 4;

    const int arow = tid >> 1;           // staging row 0..127
    const int kb = (tid & 1) * 2;        // staging kgrp base (0 or 2)

    f32x4 acc[8][4];
    #pragma unroll
    for (int a = 0; a < 8; ++a)
        #pragma unroll
        for (int b = 0; b < 4; ++b) {
            f32x4 z = {0.0f, 0.0f, 0.0f, 0.0f};
            acc[a][b] = z;
        }

    // Load 16 f32 of substep s (clamped) into 4 float4 regs.
    #define LOADX(dst, s)                                                         \
    {                                                                             \
        int s_ = (s) > 63 ? 63 : (s);                                             \
        int k0_ = s_ * 32;                                                        \
        const float* src_ = (k0_ < 1024) ? xr : xi;                               \
        const float* p_ = src_ + (size_t)(bm + arow) * DD + (k0_ & 1023)          \
                          + (tid & 1) * 16;                                       \
        (dst)[0] = *(const float4*)(p_);                                          \
        (dst)[1] = *(const float4*)(p_ + 4);                                      \
        (dst)[2] = *(const float4*)(p_ + 8);                                      \
        (dst)[3] = *(const float4*)(p_ + 12);                                     \
    }

    // Convert 16 f32 -> 8 packed bf16-pairs via v_cvt_pk_bf16_f32 (RNE),
    // write 2x b128 into buffer base bb.
    #define WRITEA(fv, bb)                                                        \
    {                                                                             \
        float ff_[16] = {(fv)[0].x, (fv)[0].y, (fv)[0].z, (fv)[0].w,              \
                         (fv)[1].x, (fv)[1].y, (fv)[1].z, (fv)[1].w,              \
                         (fv)[2].x, (fv)[2].y, (fv)[2].z, (fv)[2].w,              \
                         (fv)[3].x, (fv)[3].y, (fv)[3].z, (fv)[3].w};             \
        unsigned int w_[8];                                                       \
        _Pragma("unroll")                                                         \
        for (int q = 0; q < 8; ++q)                                               \
            asm("v_cvt_pk_bf16_f32 %0, %1, %2"                                    \
                : "=v"(w_[q]) : "v"(ff_[2*q]), "v"(ff_[2*q+1]));                  \
        _Pragma("unroll")                                                         \
        for (int b2 = 0; b2 < 2; ++b2) {                                          \
            int o_ = ((kb + b2) * 128 + arow) * 8;                                \
            *(uint4*)&lds[(bb) + o_] = make_uint4(                                \
                w_[b2*4+0], w_[b2*4+1], w_[b2*4+2], w_[b2*4+3]);                  \
        }                                                                         \
    }

    // A frag from LDS; B frag direct from L2-resident g_WTs.
    #define RA(bb, mi) (*(const bf16x8*)&lds[(bb) + \
        (sgrp * 128 + (mi) * 16 + r16) * 8])
    #define BW(s, plane, ni) (*(const bf16x8*)&g_WTs[ \
        ((size_t)((((s) > 63 ? 63 : (s)) * 2 + (plane)) * 4 + sgrp) * 1024 + \
         (bn + wc * 64 + (ni) * 16 + r16)) * 8])

    // ---- Prologue: stage substep 0; preload f32(1). ----
    float4 fst[4], ftmp[4];
    LOADX(fst, 0);
    WRITEA(fst, 0);
    LOADX(fst, 1);
    asm volatile("s_waitcnt lgkmcnt(0)" ::: "memory");
    __builtin_amdgcn_s_barrier();

    for (int st = 0; st < NST; ++st) {
        const int bcur = (st & 1) * 4096;
        const int bnxt = bcur ^ 4096;

        // Issue B(st) loads first: WRITEA's conversion VALU covers L2 latency.
        bf16x8 whf[4], wlf[4], ahi[8];
        #pragma unroll
        for (int ni = 0; ni < 4; ++ni) whf[ni] = BW(st, 0, ni);
        #pragma unroll
        for (int ni = 0; ni < 4; ++ni) wlf[ni] = BW(st, 1, ni);

        // Stage st+1 into nxt; issue f32(st+2).
        WRITEA(fst, bnxt);
        LOADX(ftmp, st + 2);

        #pragma unroll
        for (int mi = 0; mi < 8; ++mi) ahi[mi] = RA(bcur, mi);

        // term 1: hi * wh
        __builtin_amdgcn_s_setprio(1);
        #pragma unroll
        for (int mi = 0; mi < 8; ++mi)
            #pragma unroll
            for (int ni = 0; ni < 4; ++ni)
                acc[mi][ni] = __builtin_amdgcn_mfma_f32_16x16x32_bf16(
                    ahi[mi], whf[ni], acc[mi][ni], 0, 0, 0);
        __builtin_amdgcn_s_setprio(0);
        // term 2: hi * wl  (A-hi register-cached)
        __builtin_amdgcn_s_setprio(1);
        #pragma unroll
        for (int mi = 0; mi < 8; ++mi)
            #pragma unroll
            for (int ni = 0; ni < 4; ++ni)
                acc[mi][ni] = __builtin_amdgcn_mfma_f32_16x16x32_bf16(
                    ahi[mi], wlf[ni], acc[mi][ni], 0, 0, 0);
        __builtin_amdgcn_s_setprio(0);

        // A-dbuf sync (4 waves; co-resident block covers the stall).
        asm volatile("s_waitcnt lgkmcnt(0)" ::: "memory");
        __builtin_amdgcn_s_barrier();
        #pragma unroll
        for (int q = 0; q < 4; ++q) fst[q] = ftmp[q];
    }
    #undef LOADX
    #undef WRITEA
    #undef RA
    #undef BW

    // ---- Epilogue stage 1: levels -> LDS (bytes 0..4095; safe: all K-loop
    // LDS traffic completed at the final in-loop barrier). ----
    unsigned char* lvl_lds = (unsigned char*)lds;
    #pragma unroll
    for (int mi = 0; mi < 8; ++mi) {
        #pragma unroll
        for (int ni = 0; ni < 4; ++ni) {
            int nl = wc * 64 + ni * 16 + r16;          // 0..255 within tile
            float bb = bias[bn + nl];
            #pragma unroll
            for (int r = 0; r < 4; ++r) {
                float z = (acc[mi][ni][r] + bb) * 1.7015f;
                float s = 1.0f / (1.0f + expf(-z));
                s += __shfl_xor(s, 1);
                s += __shfl_xor(s, 2);
                s += __shfl_xor(s, 4);
                if ((lane & 7) == 0) {
                    float gcont = s * 0.125f;
                    int lvl = (int)rintf(gcont * 7.0f);
                    lvl = min(7, max(0, lvl));
                    int row = mi * 16 + sgrp * 4 + r;  // 0..127 within tile
                    lvl_lds[row * 32 + (nl >> 3)] = (unsigned char)lvl;
                }
            }
        }
    }
    __syncthreads();

    // ---- Epilogue stage 2: fused apply (identical math to apply_kernel).
    // Each thread rotates 16 (row, nblock) pairs; coalesced x reads/out writes.
    const int nb0 = bn >> 3;
    #pragma unroll 2
    for (int it = 0; it < 16; ++it) {
        int p = it * 256 + tid;
        int row = p >> 5;                 // 0..127
        int nbi = p & 31;                 // 0..31
        int m = bm + row;
        int nb = nb0 + nbi;
        int n0 = nb * 8;

        int L = lvl_lds[row * 32 + nbi];
        const unsigned short* Up = g_U16 + (size_t)(L * NN + nb) * 128;
        const float* xrp = xr + (size_t)m * DD + n0;
        const float* xip = xi + (size_t)m * DD + n0;

        float4 r0 = *(const float4*)xrp;
        float4 r1 = *(const float4*)(xrp + 4);
        float4 i0 = *(const float4*)xip;
        float4 i1 = *(const float4*)(xip + 4);
        float xrv[8] = {r0.x, r0.y, r0.z, r0.w, r1.x, r1.y, r1.z, r1.w};
        float xiv[8] = {i0.x, i0.y, i0.z, i0.w, i1.x, i1.y, i1.z, i1.w};

        float gq = (float)L * (1.0f / 7.0f);
        float scale = gq / (gq + 1e-7f);

        unsigned int pk[8];
        #pragma unroll
        for (int oo = 0; oo < 8; ++oo) {
            uint4 uw = *(const uint4*)&Up[oo * 8];        // 8 bf16 of U_r row
            uint4 vw = *(const uint4*)&Up[64 + oo * 8];   // 8 bf16 of U_i row
            unsigned int uwa[4] = {uw.x, uw.y, uw.z, uw.w};
            unsigned int vwa[4] = {vw.x, vw.y, vw.z, vw.w};
            float ur[8], ui[8];
            #pragma unroll
            for (int q = 0; q < 4; ++q) {
                ur[2*q]   = bfbits2f(uwa[q] & 0xFFFFu);
                ur[2*q+1] = bfbits2f(uwa[q] >> 16);
                ui[2*q]   = bfbits2f(vwa[q] & 0xFFFFu);
                ui[2*q+1] = bfbits2f(vwa[q] >> 16);
            }
            float uxr = 0.0f, uxi = 0.0f;
            #pragma unroll
            for (int q = 0; q < 8; ++q) {
                uxr += ur[q] * xrv[q] - ui[q] * xiv[q];
                uxi += ur[q] * xiv[q] + ui[q] * xrv[q];
            }
            float outr = xrv[oo] + scale * (uxr - xrv[oo]);
            float outi = xiv[oo] + scale * (uxi - xiv[oo]);
            pk[oo] = bf16_bits(outi) | (bf16_bits(outr) << 16);   // [imag, real]
        }

        unsigned int* ob = (unsigned int*)(out + 2 * ((size_t)m * DD + n0));
        *(uint4*)&ob[0] = make_uint4(pk[0], pk[1], pk[2], pk[3]);
        *(uint4*)&ob[4] = make_uint4(pk[4], pk[5], pk[6], pk[7]);
    }
}

// ---------------------------------------------------------------------------
extern "C" void kernel_launch(void* const* d_in, const int* in_sizes, int n_in,
                              void* d_out, int out_size, void* d_ws, size_t ws_size,
                              hipStream_t stream) {
    (void)in_sizes; (void)n_in; (void)out_size; (void)d_ws; (void)ws_size;
    const float* x_real = (const float*)d_in[0];
    const float* x_imag = (const float*)d_in[1];
    const float* A_real = (const float*)d_in[2];
    const float* A_imag = (const float*)d_in[3];
    const float* W_gate = (const float*)d_in[4];
    const float* b_gate = (const float*)d_in[5];
    unsigned short* out = (unsigned short*)d_out;

    hipLaunchKernelGGL(prep_kernel, dim3(WT_BLOCKS + KLV * NN), dim3(256),
                       0, stream, W_gate, A_real, A_imag);
    hipLaunchKernelGGL(gate_fused, dim3(512), dim3(256), 0, stream,
                       x_real, x_imag, b_gate, out);
}

// Round 25
// 218.609 us; speedup vs baseline: 1.3547x; 1.0056x over previous
//
#include <hip/hip_runtime.h>
#include <hip/hip_bf16.h>
#include <math.h>

// Problem constants
#define BB 4
#define SS 4096
#define DD 1024
#define NN 128           // D / 8
#define KLV 8            // quantization levels
#define MM (BB*SS)       // 16384 rows
#define NST 64           // K substeps of 32 over x_cat (2048)

typedef short bf16x8 __attribute__((ext_vector_type(8)));
typedef float f32x4 __attribute__((ext_vector_type(4)));

// Static device scratch.
__device__ unsigned short g_U16[KLV * NN * 128];   // 256 KB Cayley table (bf16)
// W pre-subtiled: elem = (((st*2 + plane)*4 + kgrp)*1024 + n)*8 + kin   (8 MB)
__device__ unsigned short g_WTs[(size_t)NST * 2 * 4 * 1024 * 8];

// f32 -> bf16 bits, round-to-nearest-even (prep-side; matches v_cvt_pk RNE)
__device__ __forceinline__ unsigned int bf16_bits(float f) {
    union { float f; unsigned int u; } v;
    v.f = f;
    unsigned int lsb = (v.u >> 16) & 1u;
    return (v.u + 0x7FFFu + lsb) >> 16;
}
__device__ __forceinline__ float bfbits2f(unsigned int b) {
    union { unsigned int u; float f; } v;
    v.u = b << 16;
    return v.f;
}

// ---------------------------------------------------------------------------
// prep_kernel: {convert_wt | cayley} by blockIdx range.
// ---------------------------------------------------------------------------
#define WT_BLOCKS (64 * 32)
__global__ __launch_bounds__(256)
void prep_kernel(const float* __restrict__ W,
                 const float* __restrict__ A_real,
                 const float* __restrict__ A_imag)
{
    __shared__ __align__(16) float sh[33 * 32];
    int blk = blockIdx.x;
    int t = threadIdx.x;

    if (blk < WT_BLOCKS) {
        // ---- convert_wt: W[k][n] -> g_WTs subtiled hi|lo (32x32 transpose) ----
        float (*tile)[33] = (float(*)[33])sh;
        int bk = (blk >> 5) * 32;
        int bn = (blk & 31) * 32;

        int kk = t >> 3;
        int nn4 = (t & 7) * 4;
        float4 v = *(const float4*)&W[(size_t)(bk + kk) * DD + bn + nn4];
        tile[kk][nn4 + 0] = v.x; tile[kk][nn4 + 1] = v.y;
        tile[kk][nn4 + 2] = v.z; tile[kk][nn4 + 3] = v.w;
        __syncthreads();

        int n2 = t >> 3;                   // 0..31 (output n within tile)
        int k4i = (t & 7) * 4;             // 0..28, 4 consecutive k
        unsigned int hi[4], lo[4];
        #pragma unroll
        for (int q = 0; q < 4; ++q) {
            float f = tile[k4i + q][n2];
            hi[q] = bf16_bits(f);
            lo[q] = bf16_bits(f - bfbits2f(hi[q]));
        }
        int st = bk >> 5;
        int kgrp = (k4i >> 3) & 3;
        int kin = k4i & 7;                 // 0 or 4
        int n = bn + n2;
        size_t bh = ((size_t)((st * 2 + 0) * 4 + kgrp) * 1024 + n) * 8 + kin;
        size_t bl = ((size_t)((st * 2 + 1) * 4 + kgrp) * 1024 + n) * 8 + kin;
        *(uint2*)&g_WTs[bh] = make_uint2(hi[0] | (hi[1] << 16), hi[2] | (hi[3] << 16));
        *(uint2*)&g_WTs[bl] = make_uint2(lo[0] | (lo[1] << 16), lo[2] | (lo[3] << 16));
        return;
    }
    blk -= WT_BLOCKS;

    {
        // ---- cayley: Gauss-Jordan on 16x16 augmented system; store bf16 ----
        float (*M)[34] = (float(*)[34])sh;
        int L = blk >> 7;
        int n = blk & 127;
        float g = (float)L * (1.0f / 7.0f);

        int i = t >> 4;
        int j = t & 15;

        const float* Ar = A_real + n * 64;
        const float* Ai = A_imag + n * 64;
        int bi = i >> 3;
        int ii = i & 7, jj = j & 7;

        float ar = (Ar[ii * 8 + jj] - Ar[jj * 8 + ii]) * 0.5f * g;
        float ai = (Ai[ii * 8 + jj] + Ai[jj * 8 + ii]) * 0.5f * g;
        float eye = (ii == jj) ? 1.0f : 0.0f;

        int bj = j >> 3;
        float lhs, rhs;
        if (bi == bj) { lhs = eye + ar; rhs = eye - ar; }
        else if (bi == 0) { lhs = -ai; rhs = ai; }
        else { lhs = ai; rhs = -ai; }

        M[i][j] = lhs;
        M[i][16 + j] = rhs;
        __syncthreads();

        for (int k = 0; k < 16; ++k) {
            float f = M[i][k] / M[k][k];
            __syncthreads();
            if (i != k) {
                M[i][j]      -= f * M[k][j];
                M[i][16 + j] -= f * M[k][16 + j];
            }
            __syncthreads();
        }

        float x = M[i][16 + j] / M[i][i];
        if (j < 8) {
            g_U16[(size_t)blk * 128 + bi * 64 + ii * 8 + j] =
                (unsigned short)bf16_bits(x);
        }
    }
}

// ---------------------------------------------------------------------------
// gate_fused: 128x256 tile, 4 waves, 2 blocks/CU, two-term split
//   z = xh*wh + xh*wl, cvt_pk conversion, apply fused in epilogue.
// Round 25: apply loop unroll 2 -> 4 (independent iterations; deeper ILP
// hides the scattered L2 U-gather latency).
// ---------------------------------------------------------------------------
__global__ __launch_bounds__(256, 2)
void gate_fused(const float* __restrict__ xr, const float* __restrict__ xi,
                const float* __restrict__ bias,
                unsigned short* __restrict__ out)
{
    __shared__ __align__(16) unsigned short lds[8192];   // 16 KB

    const int tid = threadIdx.x;
    const int bid = blockIdx.x;          // 0..511
    const int xcd = bid & 7;             // dispatch round-robins XCDs [m09]
    const int grp = bid >> 3;            // 0..63
    const int mt = xcd * 16 + (grp >> 2);// 0..127 : 4 n-tiles of an m-strip
    const int nt = grp & 3;              //          co-resident on one XCD
    const int bm = mt * 128, bn = nt * 256;

    const int lane = tid & 63;
    const int wc = tid >> 6;             // 4 waves = 4 N-columns
    const int r16 = lane & 15, sgrp = lane >> 4;

    const int arow = tid >> 1;           // staging row 0..127
    const int kb = (tid & 1) * 2;        // staging kgrp base (0 or 2)

    f32x4 acc[8][4];
    #pragma unroll
    for (int a = 0; a < 8; ++a)
        #pragma unroll
        for (int b = 0; b < 4; ++b) {
            f32x4 z = {0.0f, 0.0f, 0.0f, 0.0f};
            acc[a][b] = z;
        }

    // Load 16 f32 of substep s (clamped) into 4 float4 regs.
    #define LOADX(dst, s)                                                         \
    {                                                                             \
        int s_ = (s) > 63 ? 63 : (s);                                             \
        int k0_ = s_ * 32;                                                        \
        const float* src_ = (k0_ < 1024) ? xr : xi;                               \
        const float* p_ = src_ + (size_t)(bm + arow) * DD + (k0_ & 1023)          \
                          + (tid & 1) * 16;                                       \
        (dst)[0] = *(const float4*)(p_);                                          \
        (dst)[1] = *(const float4*)(p_ + 4);                                      \
        (dst)[2] = *(const float4*)(p_ + 8);                                      \
        (dst)[3] = *(const float4*)(p_ + 12);                                     \
    }

    // Convert 16 f32 -> 8 packed bf16-pairs via v_cvt_pk_bf16_f32 (RNE),
    // write 2x b128 into buffer base bb.
    #define WRITEA(fv, bb)                                                        \
    {                                                                             \
        float ff_[16] = {(fv)[0].x, (fv)[0].y, (fv)[0].z, (fv)[0].w,              \
                         (fv)[1].x, (fv)[1].y, (fv)[1].z, (fv)[1].w,              \
                         (fv)[2].x, (fv)[2].y, (fv)[2].z, (fv)[2].w,              \
                         (fv)[3].x, (fv)[3].y, (fv)[3].z, (fv)[3].w};             \
        unsigned int w_[8];                                                       \
        _Pragma("unroll")                                                         \
        for (int q = 0; q < 8; ++q)                                               \
            asm("v_cvt_pk_bf16_f32 %0, %1, %2"                                    \
                : "=v"(w_[q]) : "v"(ff_[2*q]), "v"(ff_[2*q+1]));                  \
        _Pragma("unroll")                                                         \
        for (int b2 = 0; b2 < 2; ++b2) {                                          \
            int o_ = ((kb + b2) * 128 + arow) * 8;                                \
            *(uint4*)&lds[(bb) + o_] = make_uint4(                                \
                w_[b2*4+0], w_[b2*4+1], w_[b2*4+2], w_[b2*4+3]);                  \
        }                                                                         \
    }

    // A frag from LDS; B frag direct from L2-resident g_WTs.
    #define RA(bb, mi) (*(const bf16x8*)&lds[(bb) + \
        (sgrp * 128 + (mi) * 16 + r16) * 8])
    #define BW(s, plane, ni) (*(const bf16x8*)&g_WTs[ \
        ((size_t)((((s) > 63 ? 63 : (s)) * 2 + (plane)) * 4 + sgrp) * 1024 + \
         (bn + wc * 64 + (ni) * 16 + r16)) * 8])

    // ---- Prologue: stage substep 0; preload f32(1). ----
    float4 fst[4], ftmp[4];
    LOADX(fst, 0);
    WRITEA(fst, 0);
    LOADX(fst, 1);
    asm volatile("s_waitcnt lgkmcnt(0)" ::: "memory");
    __builtin_amdgcn_s_barrier();

    for (int st = 0; st < NST; ++st) {
        const int bcur = (st & 1) * 4096;
        const int bnxt = bcur ^ 4096;

        // Issue B(st) loads first: WRITEA's conversion VALU covers L2 latency.
        bf16x8 whf[4], wlf[4], ahi[8];
        #pragma unroll
        for (int ni = 0; ni < 4; ++ni) whf[ni] = BW(st, 0, ni);
        #pragma unroll
        for (int ni = 0; ni < 4; ++ni) wlf[ni] = BW(st, 1, ni);

        // Stage st+1 into nxt; issue f32(st+2).
        WRITEA(fst, bnxt);
        LOADX(ftmp, st + 2);

        #pragma unroll
        for (int mi = 0; mi < 8; ++mi) ahi[mi] = RA(bcur, mi);

        // term 1: hi * wh
        __builtin_amdgcn_s_setprio(1);
        #pragma unroll
        for (int mi = 0; mi < 8; ++mi)
            #pragma unroll
            for (int ni = 0; ni < 4; ++ni)
                acc[mi][ni] = __builtin_amdgcn_mfma_f32_16x16x32_bf16(
                    ahi[mi], whf[ni], acc[mi][ni], 0, 0, 0);
        __builtin_amdgcn_s_setprio(0);
        // term 2: hi * wl  (A-hi register-cached)
        __builtin_amdgcn_s_setprio(1);
        #pragma unroll
        for (int mi = 0; mi < 8; ++mi)
            #pragma unroll
            for (int ni = 0; ni < 4; ++ni)
                acc[mi][ni] = __builtin_amdgcn_mfma_f32_16x16x32_bf16(
                    ahi[mi], wlf[ni], acc[mi][ni], 0, 0, 0);
        __builtin_amdgcn_s_setprio(0);

        // A-dbuf sync (4 waves; co-resident block covers the stall).
        asm volatile("s_waitcnt lgkmcnt(0)" ::: "memory");
        __builtin_amdgcn_s_barrier();
        #pragma unroll
        for (int q = 0; q < 4; ++q) fst[q] = ftmp[q];
    }
    #undef LOADX
    #undef WRITEA
    #undef RA
    #undef BW

    // ---- Epilogue stage 1: levels -> LDS (bytes 0..4095; safe: all K-loop
    // LDS traffic completed at the final in-loop barrier). ----
    unsigned char* lvl_lds = (unsigned char*)lds;
    #pragma unroll
    for (int mi = 0; mi < 8; ++mi) {
        #pragma unroll
        for (int ni = 0; ni < 4; ++ni) {
            int nl = wc * 64 + ni * 16 + r16;          // 0..255 within tile
            float bb = bias[bn + nl];
            #pragma unroll
            for (int r = 0; r < 4; ++r) {
                float z = (acc[mi][ni][r] + bb) * 1.7015f;
                float s = 1.0f / (1.0f + expf(-z));
                s += __shfl_xor(s, 1);
                s += __shfl_xor(s, 2);
                s += __shfl_xor(s, 4);
                if ((lane & 7) == 0) {
                    float gcont = s * 0.125f;
                    int lvl = (int)rintf(gcont * 7.0f);
                    lvl = min(7, max(0, lvl));
                    int row = mi * 16 + sgrp * 4 + r;  // 0..127 within tile
                    lvl_lds[row * 32 + (nl >> 3)] = (unsigned char)lvl;
                }
            }
        }
    }
    __syncthreads();

    // ---- Epilogue stage 2: fused apply (identical math to apply_kernel).
    // 16 independent iterations; unroll 4 so 4 scattered U-gathers are in
    // flight while earlier iterations' rotation VALU executes.
    const int nb0 = bn >> 3;
    #pragma unroll 4
    for (int it = 0; it < 16; ++it) {
        int p = it * 256 + tid;
        int row = p >> 5;                 // 0..127
        int nbi = p & 31;                 // 0..31
        int m = bm + row;
        int nb = nb0 + nbi;
        int n0 = nb * 8;

        int L = lvl_lds[row * 32 + nbi];
        const unsigned short* Up = g_U16 + (size_t)(L * NN + nb) * 128;
        const float* xrp = xr + (size_t)m * DD + n0;
        const float* xip = xi + (size_t)m * DD + n0;

        float4 r0 = *(const float4*)xrp;
        float4 r1 = *(const float4*)(xrp + 4);
        float4 i0 = *(const float4*)xip;
        float4 i1 = *(const float4*)(xip + 4);
        float xrv[8] = {r0.x, r0.y, r0.z, r0.w, r1.x, r1.y, r1.z, r1.w};
        float xiv[8] = {i0.x, i0.y, i0.z, i0.w, i1.x, i1.y, i1.z, i1.w};

        float gq = (float)L * (1.0f / 7.0f);
        float scale = gq / (gq + 1e-7f);

        unsigned int pk[8];
        #pragma unroll
        for (int oo = 0; oo < 8; ++oo) {
            uint4 uw = *(const uint4*)&Up[oo * 8];        // 8 bf16 of U_r row
            uint4 vw = *(const uint4*)&Up[64 + oo * 8];   // 8 bf16 of U_i row
            unsigned int uwa[4] = {uw.x, uw.y, uw.z, uw.w};
            unsigned int vwa[4] = {vw.x, vw.y, vw.z, vw.w};
            float ur[8], ui[8];
            #pragma unroll
            for (int q = 0; q < 4; ++q) {
                ur[2*q]   = bfbits2f(uwa[q] & 0xFFFFu);
                ur[2*q+1] = bfbits2f(uwa[q] >> 16);
                ui[2*q]   = bfbits2f(vwa[q] & 0xFFFFu);
                ui[2*q+1] = bfbits2f(vwa[q] >> 16);
            }
            float uxr = 0.0f, uxi = 0.0f;
            #pragma unroll
            for (int q = 0; q < 8; ++q) {
                uxr += ur[q] * xrv[q] - ui[q] * xiv[q];
                uxi += ur[q] * xiv[q] + ui[q] * xrv[q];
            }
            float outr = xrv[oo] + scale * (uxr - xrv[oo]);
            float outi = xiv[oo] + scale * (uxi - xiv[oo]);
            pk[oo] = bf16_bits(outi) | (bf16_bits(outr) << 16);   // [imag, real]
        }

        unsigned int* ob = (unsigned int*)(out + 2 * ((size_t)m * DD + n0));
        *(uint4*)&ob[0] = make_uint4(pk[0], pk[1], pk[2], pk[3]);
        *(uint4*)&ob[4] = make_uint4(pk[4], pk[5], pk[6], pk[7]);
    }
}

// ---------------------------------------------------------------------------
extern "C" void kernel_launch(void* const* d_in, const int* in_sizes, int n_in,
                              void* d_out, int out_size, void* d_ws, size_t ws_size,
                              hipStream_t stream) {
    (void)in_sizes; (void)n_in; (void)out_size; (void)d_ws; (void)ws_size;
    const float* x_real = (const float*)d_in[0];
    const float* x_imag = (const float*)d_in[1];
    const float* A_real = (const float*)d_in[2];
    const float* A_imag = (const float*)d_in[3];
    const float* W_gate = (const float*)d_in[4];
    const float* b_gate = (const float*)d_in[5];
    unsigned short* out = (unsigned short*)d_out;

    hipLaunchKernelGGL(prep_kernel, dim3(WT_BLOCKS + KLV * NN), dim3(256),
                       0, stream, W_gate, A_real, A_imag);
    hipLaunchKernelGGL(gate_fused, dim3(512), dim3(256), 0, stream,
                       x_real, x_imag, b_gate, out);
}